// Round 10
// baseline (401.188 us; speedup 1.0000x reference)
//
#include <hip/hip_runtime.h>
#include <stdint.h>

// Problem constants
#define B_SZ  4
#define T_SEQ 2048
#define DIM   1024
#define NH    16
#define HD    64
#define M_TOT (B_SZ * T_SEQ)   // 8192

typedef unsigned short u16;
typedef unsigned long long u64;
typedef __attribute__((ext_vector_type(8))) __bf16 bf16x8;   // MFMA A/B frag (4 VGPR)
typedef __attribute__((ext_vector_type(4))) float  floatx4;  // MFMA C/D frag 16x16
typedef __attribute__((ext_vector_type(16))) float floatx16; // MFMA C/D frag 32x32

#define SCL_Q (0.125f * 1.44269504089f)   // 1/sqrt(HD) * log2(e), folded into q

__device__ __forceinline__ u16 f2bf(float f) {
  union { float f; uint32_t u; } v; v.f = f;
  uint32_t r = v.u + 0x7fffu + ((v.u >> 16) & 1u);   // RNE
  return (u16)(r >> 16);
}

// async global->LDS, 16B per lane; LDS dest = uniform base + lane*16
__device__ __forceinline__ void gl_lds16(const void* g, void* l) {
  __builtin_amdgcn_global_load_lds(
      (const __attribute__((address_space(1))) uint32_t*)g,
      (__attribute__((address_space(3))) uint32_t*)l, 16, 0, 0);
}

// ---------------------------------------------------------------- converts
// WEIGHTS ONLY: activations are now consumed as f32 directly by gemm_qkv
// (staged via global_load_lds — the pipelining-safe path, unlike round-7's
// failed reg-load variant). Removes 144MB of activation cvt traffic (~30us).
__global__ __launch_bounds__(256) void cvt_w(
    const float* __restrict__ s0, const float* __restrict__ s1,
    const float* __restrict__ s2, const float* __restrict__ s3,
    u16* __restrict__ d0, u16* __restrict__ d1, u16* __restrict__ d2,
    u16* __restrict__ d3) {
  const float* s; u16* d;
  switch (blockIdx.y) {
    case 0: s = s0; d = d0; break;
    case 1: s = s1; d = d1; break;
    case 2: s = s2; d = d2; break;
    default: s = s3; d = d3; break;
  }
  int i = (blockIdx.x * 256 + threadIdx.x) * 8;
  float4 a = *(const float4*)(s + i);
  float4 b = *(const float4*)(s + i + 4);
  uint4 o;
  o.x = (uint32_t)f2bf(a.x) | ((uint32_t)f2bf(a.y) << 16);
  o.y = (uint32_t)f2bf(a.z) | ((uint32_t)f2bf(a.w) << 16);
  o.z = (uint32_t)f2bf(b.x) | ((uint32_t)f2bf(b.y) << 16);
  o.w = (uint32_t)f2bf(b.z) | ((uint32_t)f2bf(b.w) << 16);
  *(uint4*)(d + i) = o;
}

// ---------------------------------------------------------------- QKV GEMM v10
// Same proven 128x128/BK=64 2-barrier structure (687 TF baseline), with ONE
// dataflow change: the A-operand (activations) is staged as F32 from the
// ORIGINAL Q/K/V via global_load_lds (48KB LDS: As 32KB f32 + Bs 16KB bf16),
// converted f32->bf16 in-register after the ds_read (RNE — identical to
// f2bf). No new sync logic. This deletes cvt_all's 144MB activation pass.
// A-swizzle for 256B rows: LDS[r][chunk c] = G[r][c ^ ((r&7)<<1)] — XOR
// above bit0 keeps each 32B read-pair contiguous; 16 rows -> 8 bank-pair
// positions = 2-way alias (free, m136).
#define BKG 64
__global__ __launch_bounds__(256) void gemm_qkv(
    const float* __restrict__ Qf, const float* __restrict__ Kf,
    const float* __restrict__ Vf,
    const u16* __restrict__ Wq, const u16* __restrict__ Wk,
    const u16* __restrict__ Wv,
    const float* __restrict__ bq, const float* __restrict__ bk,
    const float* __restrict__ bv,
    u16* __restrict__ qo, u16* __restrict__ ko, u16* __restrict__ vo) {
  const float* Af; const u16* Bw; const float* bias; u16* Co;
  if (blockIdx.z == 0)      { Af = Qf; Bw = Wq; bias = bq; Co = qo; }
  else if (blockIdx.z == 1) { Af = Kf; Bw = Wk; bias = bk; Co = ko; }
  else                      { Af = Vf; Bw = Wv; bias = bv; Co = vo; }

  __shared__ float Asf[128 * 64];   // A tile f32, 32 KB
  __shared__ u16   Bs[128 * 64];    // B tile bf16, 16 KB

  const int tid  = threadIdx.x;
  const int wave = tid >> 6, lane = tid & 63;
  const int quad = lane >> 4, l16 = lane & 15;
  const int wm = wave >> 1, wn = wave & 1;
  const int m0 = blockIdx.x * 128, n0 = blockIdx.y * 128;

  const floatx4 FZ = {0.f, 0.f, 0.f, 0.f};
  floatx4 acc[4][4];
#pragma unroll
  for (int mt = 0; mt < 4; ++mt)
#pragma unroll
    for (int nt = 0; nt < 4; ++nt) acc[mt][nt] = FZ;

  for (int k0 = 0; k0 < DIM; k0 += BKG) {
    __syncthreads();
    // ---- stage A f32: 8 calls/thread; row r (256B = 16 chunks of 16B),
    //      source chunk = c ^ ((r&7)<<1); dest linear (4 rows per wave-call)
#pragma unroll
    for (int j = 0; j < 8; ++j) {
      int pc = j * 256 + tid;
      int r = pc >> 4, c = pc & 15;
      int sc = c ^ ((r & 7) << 1);
      gl_lds16(Af + (size_t)(m0 + r) * DIM + k0 + sc * 4,
               &Asf[(size_t)(j * 16 + wave * 4) * 64]);
    }
    // ---- stage B bf16: 4 calls/thread (unchanged)
#pragma unroll
    for (int j = 0; j < 4; ++j) {
      int pc = j * 256 + tid;
      int r = pc >> 3, c = pc & 7;
      int sc = c ^ (r & 7);
      gl_lds16(Bw + (size_t)(n0 + r) * DIM + k0 + sc * 8,
               &Bs[(j * 256 + wave * 64) * 8]);
    }
    __syncthreads();

#pragma unroll
    for (int kk = 0; kk < 2; ++kk) {
      bf16x8 af[4], bfr[4];
#pragma unroll
      for (int mt = 0; mt < 4; ++mt) {
        int ra = wm * 64 + mt * 16 + l16;
        int c0 = (quad * 2 + kk * 8) ^ ((ra & 7) << 1);   // even -> pair OK
        const float* ap = &Asf[(size_t)ra * 64 + c0 * 4];
        float4 lo = *(const float4*)ap;
        float4 hi = *(const float4*)(ap + 4);
        bf16x8 a;
        a[0] = (__bf16)lo.x; a[1] = (__bf16)lo.y;
        a[2] = (__bf16)lo.z; a[3] = (__bf16)lo.w;
        a[4] = (__bf16)hi.x; a[5] = (__bf16)hi.y;
        a[6] = (__bf16)hi.z; a[7] = (__bf16)hi.w;
        af[mt] = a;
      }
#pragma unroll
      for (int nt = 0; nt < 4; ++nt) {
        int rb = wn * 64 + nt * 16 + l16;
        bfr[nt] = *(const bf16x8*)&Bs[rb * 64 + (((kk * 4 + quad) ^ (rb & 7)) * 8)];
      }
#pragma unroll
      for (int mt = 0; mt < 4; ++mt)
#pragma unroll
        for (int nt = 0; nt < 4; ++nt)
          acc[mt][nt] = __builtin_amdgcn_mfma_f32_16x16x32_bf16(
              af[mt], bfr[nt], acc[mt][nt], 0, 0, 0);
    }
  }

  if (blockIdx.z == 2) {
    // V: transposed store to [B,H,HD,T], 8B packed (4 consecutive t)
#pragma unroll
    for (int nt = 0; nt < 4; ++nt) {
      int n = n0 + wn * 64 + nt * 16 + l16;
      float bb = bias[n];
      int h = n >> 6, hd = n & 63;
#pragma unroll
      for (int mt = 0; mt < 4; ++mt) {
        int mbase = m0 + wm * 64 + mt * 16 + quad * 4;
        int b = mbase >> 11, t = mbase & (T_SEQ - 1);
        u64 pk = 0;
#pragma unroll
        for (int r = 0; r < 4; ++r)
          pk |= (u64)f2bf(acc[mt][nt][r] + bb) << (16 * r);
        *(u64*)&Co[((size_t)((b * NH + h) * HD + hd)) * T_SEQ + t] = pk;
      }
    }
  } else {
    // Q/K: +bias (Q also * SCL_Q), bf16, scatter to [B,H,T,HD]
    const float sc = (blockIdx.z == 0) ? SCL_Q : 1.0f;
#pragma unroll
    for (int nt = 0; nt < 4; ++nt) {
      int n = n0 + wn * 64 + nt * 16 + l16;
      float bb = bias[n];
      int h = n >> 6, hd = n & 63;
#pragma unroll
      for (int mt = 0; mt < 4; ++mt) {
#pragma unroll
        for (int r = 0; r < 4; ++r) {
          int m = m0 + wm * 64 + mt * 16 + quad * 4 + r;
          int b = m >> 11, t = m & (T_SEQ - 1);
          Co[((size_t)(b * NH + h) * T_SEQ + t) * HD + hd] =
              f2bf((acc[mt][nt][r] + bb) * sc);
        }
      }
    }
  }
}

// ---------------------------------------------------------------- flash attn
// v4 (proven): 4 waves x 64 q-cols per wave (two 32-col q-sets per lane),
// 256 thr, 3-deep K/V pipeline, counted vmcnt(4), fixed-max softmax,
// permlane P-transpose. 512 blocks co-resident; heavy+light qt pairing.
__global__ __launch_bounds__(256, 2) void flash_attn(
    const u16* __restrict__ qp, const u16* __restrict__ kp,
    const u16* __restrict__ vp, u16* __restrict__ ao) {
  const int bh = blockIdx.x;                       // 0..63
  const int y = blockIdx.y;                        // 0..7
  const int qt = (y < 4) ? (7 - y) : (y - 4);      // heavy first + pairing
  const int b = bh >> 4, h = bh & 15;
  const u16* Qg = qp + (size_t)bh * T_SEQ * HD;
  const u16* Kg = kp + (size_t)bh * T_SEQ * HD;
  const u16* Vg = vp + (size_t)bh * HD * T_SEQ;    // [hd][t]

  __shared__ u16 lds[6][64 * 64];   // {K,V} x 3-deep, 48 KB

  const int tid = threadIdx.x, wave = tid >> 6, lane = tid & 63;
  const int hi = lane >> 5, c31 = lane & 31;
  const int lr8 = lane >> 3, lc8 = lane & 7;

  const int wbase = qt * 256 + wave * 64;   // wave's 64 q rows
  const int qrowA = wbase + c31;            // q-set A
  const int qrowB = qrowA + 32;             // q-set B

  bf16x8 bqA[4], bqB[4];
#pragma unroll
  for (int cth = 0; cth < 4; ++cth) {
    bqA[cth] = *(const bf16x8*)(Qg + (size_t)qrowA * HD + cth * 16 + hi * 8);
    bqB[cth] = *(const bf16x8*)(Qg + (size_t)qrowB * HD + cth * 16 + hi * 8);
  }

  const int nkb = 4 * qt + 4;   // kv tiles (>=4)

#define STAGE_KV(kbidx, bufpair)                                              \
  {                                                                           \
    const u16* Kgk = Kg + (size_t)(kbidx) * 64 * HD;                          \
    const u16* Vgk = Vg + (size_t)(kbidx) * 64;                               \
    _Pragma("unroll") for (int i_ = 0; i_ < 2; ++i_) {                        \
      int r_ = i_ * 32 + wave * 8 + lr8;                                      \
      int sc_ = lc8 ^ (r_ & 7);                                               \
      gl_lds16(Kgk + (size_t)r_ * HD + sc_ * 8,                               \
               &lds[(bufpair) * 2][(i_ * 32 + wave * 8) * 64]);               \
      gl_lds16(Vgk + (size_t)r_ * T_SEQ + sc_ * 8,                            \
               &lds[(bufpair) * 2 + 1][(i_ * 32 + wave * 8) * 64]);           \
    }                                                                         \
  }

  STAGE_KV(0, 0);
  STAGE_KV(1, 1);

  asm volatile("" :: "v"(bqA[0]), "v"(bqA[1]), "v"(bqA[2]), "v"(bqA[3]),
                     "v"(bqB[0]), "v"(bqB[1]), "v"(bqB[2]), "v"(bqB[3]));

  floatx16 oA0, oA1, oB0, oB1;   // O^T accum per set: hd 0..31 / 32..63
#pragma unroll
  for (int i = 0; i < 16; ++i) { oA0[i] = 0.f; oA1[i] = 0.f;
                                 oB0[i] = 0.f; oB1[i] = 0.f; }
  float l_pA = 0.f, l_pB = 0.f;  // lane-local softmax denominators

  int koff[4];
#pragma unroll
  for (int x = 0; x < 4; ++x)
    koff[x] = c31 * 64 + (((x * 2 + hi) ^ (c31 & 7)) * 8);

  int pcb = 0;   // compute buffer-pair
  int psb = 2;   // next stage buffer-pair
  for (int kb = 0; kb < nkb; ++kb) {
    if (kb + 1 < nkb) asm volatile("s_waitcnt vmcnt(4)" ::: "memory");
    else              asm volatile("s_waitcnt vmcnt(0)" ::: "memory");
    __builtin_amdgcn_s_barrier();
    __builtin_amdgcn_sched_barrier(0);

    if (kb + 2 < nkb) {   // stage tile kb+2 (lands ~2 compute phases later)
      STAGE_KV(kb + 2, psb);
      psb = (psb == 2) ? 0 : psb + 1;
    }

    if (kb * 64 <= wbase + 63) {
      const u16* Ks = &lds[pcb * 2][0];
      const u16* Vs = &lds[pcb * 2 + 1][0];

      floatx16 sA0, sA1, sB0, sB1;
#pragma unroll
      for (int i = 0; i < 16; ++i) { sA0[i] = 0.f; sA1[i] = 0.f;
                                     sB0[i] = 0.f; sB1[i] = 0.f; }
#pragma unroll
      for (int cth = 0; cth < 4; ++cth) {
        bf16x8 ka = *(const bf16x8*)&Ks[koff[cth]];
        bf16x8 kh = *(const bf16x8*)&Ks[koff[cth] + 32 * 64];
        sA0 = __builtin_amdgcn_mfma_f32_32x32x16_bf16(ka, bqA[cth], sA0, 0, 0, 0);
        sA1 = __builtin_amdgcn_mfma_f32_32x32x16_bf16(kh, bqA[cth], sA1, 0, 0, 0);
        sB0 = __builtin_amdgcn_mfma_f32_32x32x16_bf16(ka, bqB[cth], sB0, 0, 0, 0);
        sB1 = __builtin_amdgcn_mfma_f32_32x32x16_bf16(kh, bqB[cth], sB1, 0, 0, 0);
      }

      if (kb * 64 + 63 > wbase) {
        int kvb = kb * 64 + 4 * hi;
#pragma unroll
        for (int r = 0; r < 16; ++r) {
          int kvr = kvb + (r & 3) + 8 * (r >> 2);
          if (kvr > qrowA)      sA0[r] = -3e38f;
          if (kvr + 32 > qrowA) sA1[r] = -3e38f;
          if (kvr > qrowB)      sB0[r] = -3e38f;
          if (kvr + 32 > qrowB) sB1[r] = -3e38f;
        }
      }

      uint32_t pkA0[8], pkA1[8], pkB0[8], pkB1[8];
      float rsA = 0.f, rsB = 0.f;
#pragma unroll
      for (int rr = 0; rr < 8; ++rr) {
        union { float f; uint32_t u; } x0, x1, y0, y1;
        x0.f = __builtin_amdgcn_exp2f(sA0[2 * rr]);
        x1.f = __builtin_amdgcn_exp2f(sA0[2 * rr + 1]);
        y0.f = __builtin_amdgcn_exp2f(sA1[2 * rr]);
        y1.f = __builtin_amdgcn_exp2f(sA1[2 * rr + 1]);
        rsA += (x0.f + x1.f) + (y0.f + y1.f);
        pkA0[rr] = __builtin_amdgcn_perm(x1.u, x0.u, 0x07060302);
        pkA1[rr] = __builtin_amdgcn_perm(y1.u, y0.u, 0x07060302);
        x0.f = __builtin_amdgcn_exp2f(sB0[2 * rr]);
        x1.f = __builtin_amdgcn_exp2f(sB0[2 * rr + 1]);
        y0.f = __builtin_amdgcn_exp2f(sB1[2 * rr]);
        y1.f = __builtin_amdgcn_exp2f(sB1[2 * rr + 1]);
        rsB += (x0.f + x1.f) + (y0.f + y1.f);
        pkB0[rr] = __builtin_amdgcn_perm(x1.u, x0.u, 0x07060302);
        pkB1[rr] = __builtin_amdgcn_perm(y1.u, y0.u, 0x07060302);
      }
      l_pA += rsA;
      l_pB += rsB;

#pragma unroll
      for (int cc = 0; cc < 4; ++cc) {
        const uint32_t* pA = (cc & 2) ? pkA1 : pkA0;
        const uint32_t* pB = (cc & 2) ? pkB1 : pkB0;
        const int e4 = (cc & 1) * 4;
        auto a0 = __builtin_amdgcn_permlane32_swap(pA[e4 + 0], pA[e4 + 2],
                                                   false, false);
        auto a1 = __builtin_amdgcn_permlane32_swap(pA[e4 + 1], pA[e4 + 3],
                                                   false, false);
        auto b0 = __builtin_amdgcn_permlane32_swap(pB[e4 + 0], pB[e4 + 2],
                                                   false, false);
        auto b1 = __builtin_amdgcn_permlane32_swap(pB[e4 + 1], pB[e4 + 3],
                                                   false, false);
        union { uint32_t u[4]; bf16x8 v; } bpA, bpB;
        bpA.u[0] = a0[0]; bpA.u[1] = a1[0]; bpA.u[2] = a0[1]; bpA.u[3] = a1[1];
        bpB.u[0] = b0[0]; bpB.u[1] = b1[0]; bpB.u[2] = b0[1]; bpB.u[3] = b1[1];
        bf16x8 va = *(const bf16x8*)&Vs[koff[cc]];
        bf16x8 vb = *(const bf16x8*)&Vs[koff[cc] + 32 * 64];
        oA0 = __builtin_amdgcn_mfma_f32_32x32x16_bf16(va, bpA.v, oA0, 0, 0, 0);
        oA1 = __builtin_amdgcn_mfma_f32_32x32x16_bf16(vb, bpA.v, oA1, 0, 0, 0);
        oB0 = __builtin_amdgcn_mfma_f32_32x32x16_bf16(va, bpB.v, oB0, 0, 0, 0);
        oB1 = __builtin_amdgcn_mfma_f32_32x32x16_bf16(vb, bpB.v, oB1, 0, 0, 0);
      }
    }
    pcb = (pcb == 2) ? 0 : pcb + 1;
  }
#undef STAGE_KV

  {
    float lA = l_pA + __shfl_xor(l_pA, 32);
    float lB = l_pB + __shfl_xor(l_pB, 32);
    float invA = 1.0f / lA, invB = 1.0f / lB;
    const size_t obaseA = (size_t)(b * T_SEQ + qrowA) * DIM + h * HD;
    const size_t obaseB = obaseA + (size_t)32 * DIM;
#pragma unroll
    for (int u4 = 0; u4 < 4; ++u4) {
      u64 wA0 = 0, wA1 = 0, wB0 = 0, wB1 = 0;
#pragma unroll
      for (int r = 0; r < 4; ++r) {
        wA0 |= (u64)f2bf(oA0[4 * u4 + r] * invA) << (16 * r);
        wA1 |= (u64)f2bf(oA1[4 * u4 + r] * invA) << (16 * r);
        wB0 |= (u64)f2bf(oB0[4 * u4 + r] * invB) << (16 * r);
        wB1 |= (u64)f2bf(oB1[4 * u4 + r] * invB) << (16 * r);
      }
      *(u64*)&ao[obaseA + 8 * u4 + 4 * hi] = wA0;
      *(u64*)&ao[obaseA + 32 + 8 * u4 + 4 * hi] = wA1;
      *(u64*)&ao[obaseB + 8 * u4 + 4 * hi] = wB0;
      *(u64*)&ao[obaseB + 32 + 8 * u4 + 4 * hi] = wB1;
    }
  }
}

// ---------------------------------------------------------------- out GEMM
// (unchanged 2-barrier 128x128 BK=64)
__global__ __launch_bounds__(256) void gemm_out(
    const u16* __restrict__ Ain, const u16* __restrict__ Wo,
    const float* __restrict__ bo, float* __restrict__ out) {
  __shared__ u16 As[128 * 64];
  __shared__ u16 Bs[128 * 64];

  const int tid  = threadIdx.x;
  const int wave = tid >> 6, lane = tid & 63;
  const int quad = lane >> 4, l16 = lane & 15;
  const int wm = wave >> 1, wn = wave & 1;
  const int m0 = blockIdx.x * 128, n0 = blockIdx.y * 128;

  const floatx4 FZ = {0.f, 0.f, 0.f, 0.f};
  floatx4 acc[4][4];
#pragma unroll
  for (int mt = 0; mt < 4; ++mt)
#pragma unroll
    for (int nt = 0; nt < 4; ++nt) acc[mt][nt] = FZ;

  for (int k0 = 0; k0 < DIM; k0 += BKG) {
    __syncthreads();
#pragma unroll
    for (int j = 0; j < 4; ++j) {
      int pc = j * 256 + tid;
      int r = pc >> 3, c = pc & 7;
      int sc = c ^ (r & 7);
      gl_lds16(Ain + (size_t)(m0 + r) * DIM + k0 + sc * 8,
               &As[(j * 256 + wave * 64) * 8]);
      gl_lds16(Wo  + (size_t)(n0 + r) * DIM + k0 + sc * 8,
               &Bs[(j * 256 + wave * 64) * 8]);
    }
    __syncthreads();

#pragma unroll
    for (int kk = 0; kk < 2; ++kk) {
      bf16x8 af[4], bfr[4];
#pragma unroll
      for (int mt = 0; mt < 4; ++mt) {
        int ra = wm * 64 + mt * 16 + l16;
        af[mt] = *(const bf16x8*)&As[ra * 64 + (((kk * 4 + quad) ^ (ra & 7)) * 8)];
      }
#pragma unroll
      for (int nt = 0; nt < 4; ++nt) {
        int rb = wn * 64 + nt * 16 + l16;
        bfr[nt] = *(const bf16x8*)&Bs[rb * 64 + (((kk * 4 + quad) ^ (rb & 7)) * 8)];
      }
#pragma unroll
      for (int mt = 0; mt < 4; ++mt)
#pragma unroll
        for (int nt = 0; nt < 4; ++nt)
          acc[mt][nt] = __builtin_amdgcn_mfma_f32_16x16x32_bf16(
              af[mt], bfr[nt], acc[mt][nt], 0, 0, 0);
    }
  }

#pragma unroll
  for (int nt = 0; nt < 4; ++nt) {
    int n = n0 + wn * 64 + nt * 16 + l16;
    float bb = bo[n];
#pragma unroll
    for (int mt = 0; mt < 4; ++mt)
#pragma unroll
      for (int r = 0; r < 4; ++r) {
        int m = m0 + wm * 64 + mt * 16 + quad * 4 + r;
        out[(size_t)m * DIM + n] = acc[mt][nt][r] + bb;
      }
  }
}

// ---------------------------------------------------------------- launch
extern "C" void kernel_launch(void* const* d_in, const int* in_sizes, int n_in,
                              void* d_out, int out_size, void* d_ws,
                              size_t ws_size, hipStream_t stream) {
  const float* Q  = (const float*)d_in[0];
  const float* K  = (const float*)d_in[1];
  const float* V  = (const float*)d_in[2];
  // d_in[3] = mask: tril causal, implemented analytically in flash_attn
  const float* Wq = (const float*)d_in[4];
  const float* bq = (const float*)d_in[5];
  const float* Wk = (const float*)d_in[6];
  const float* bk = (const float*)d_in[7];
  const float* Wv = (const float*)d_in[8];
  const float* bv = (const float*)d_in[9];
  const float* Wo = (const float*)d_in[10];
  const float* bo = (const float*)d_in[11];
  float* out = (float*)d_out;

  // workspace layout (u16 elements)
  u16* wqb = (u16*)d_ws;
  u16* wkb = wqb + 1048576;
  u16* wvb = wkb + 1048576;
  u16* wob = wvb + 1048576;
  u16* qp  = wob + 1048576;             // projected [B,H,T,HD] (q pre-scaled)
  u16* kp  = qp + (size_t)M_TOT * DIM;  // [B,H,T,HD]
  u16* vp  = kp + (size_t)M_TOT * DIM;  // [B,H,HD,T]  (pre-transposed)
  u16* aop = vp + (size_t)M_TOT * DIM;  // attn out [B,T,D] bf16

  cvt_w<<<dim3(DIM * DIM / 2048, 4), 256, 0, stream>>>(
      Wq, Wk, Wv, Wo, wqb, wkb, wvb, wob);

  gemm_qkv<<<dim3(M_TOT / 128, DIM / 128, 3), 256, 0, stream>>>(
      Q, K, V, wqb, wkb, wvb, bq, bk, bv, qp, kp, vp);

  flash_attn<<<dim3(B_SZ * NH, T_SEQ / 256), 256, 0, stream>>>(qp, kp, vp, aop);

  gemm_out<<<dim3(M_TOT / 128, DIM / 128), 256, 0, stream>>>(aop, wob, bo, out);
}

// Round 11
// 308.043 us; speedup vs baseline: 1.3024x; 1.3024x over previous
//
#include <hip/hip_runtime.h>
#include <stdint.h>

// Problem constants
#define B_SZ  4
#define T_SEQ 2048
#define DIM   1024
#define NH    16
#define HD    64
#define M_TOT (B_SZ * T_SEQ)   // 8192

typedef unsigned short u16;
typedef unsigned long long u64;
typedef __attribute__((ext_vector_type(8))) __bf16 bf16x8;   // MFMA A/B frag (4 VGPR)
typedef __attribute__((ext_vector_type(4))) float  floatx4;  // MFMA C/D frag 16x16
typedef __attribute__((ext_vector_type(16))) float floatx16; // MFMA C/D frag 32x32

#define SCL_Q (0.125f * 1.44269504089f)   // 1/sqrt(HD) * log2(e), folded into q

__device__ __forceinline__ u16 f2bf(float f) {
  union { float f; uint32_t u; } v; v.f = f;
  uint32_t r = v.u + 0x7fffu + ((v.u >> 16) & 1u);   // RNE
  return (u16)(r >> 16);
}

// async global->LDS, 16B per lane; LDS dest = uniform base + lane*16
__device__ __forceinline__ void gl_lds16(const void* g, void* l) {
  __builtin_amdgcn_global_load_lds(
      (const __attribute__((address_space(1))) uint32_t*)g,
      (__attribute__((address_space(3))) uint32_t*)l, 16, 0, 0);
}

// ---------------------------------------------------------------- converts
// One dispatch converts all 7 f32 tensors to bf16:
// y=0..3 -> weights (1M elems), y=4..6 -> activations Q,K,V (8M elems).
// (v10's f32-staged-A alternative regressed 75->212us: wrong bank swizzle
// for 256B rows -> 6.1e7 LDS conflicts; even fixed, the +LDS traffic and
// f32 re-fetch are ~break-even. This cvt+bf16-staging dataflow is final.)
__global__ __launch_bounds__(256) void cvt_all(
    const float* __restrict__ s0, const float* __restrict__ s1,
    const float* __restrict__ s2, const float* __restrict__ s3,
    const float* __restrict__ s4, const float* __restrict__ s5,
    const float* __restrict__ s6,
    u16* __restrict__ d0, u16* __restrict__ d1, u16* __restrict__ d2,
    u16* __restrict__ d3, u16* __restrict__ d4, u16* __restrict__ d5,
    u16* __restrict__ d6) {
  const float* s; u16* d; int n;
  switch (blockIdx.y) {
    case 0: s = s0; d = d0; n = DIM * DIM; break;
    case 1: s = s1; d = d1; n = DIM * DIM; break;
    case 2: s = s2; d = d2; n = DIM * DIM; break;
    case 3: s = s3; d = d3; n = DIM * DIM; break;
    case 4: s = s4; d = d4; n = M_TOT * DIM; break;
    case 5: s = s5; d = d5; n = M_TOT * DIM; break;
    default: s = s6; d = d6; n = M_TOT * DIM; break;
  }
  int i = (blockIdx.x * 256 + threadIdx.x) * 8;
  if (i >= n) return;
  float4 a = *(const float4*)(s + i);
  float4 b = *(const float4*)(s + i + 4);
  uint4 o;
  o.x = (uint32_t)f2bf(a.x) | ((uint32_t)f2bf(a.y) << 16);
  o.y = (uint32_t)f2bf(a.z) | ((uint32_t)f2bf(a.w) << 16);
  o.z = (uint32_t)f2bf(b.x) | ((uint32_t)f2bf(b.y) << 16);
  o.w = (uint32_t)f2bf(b.z) | ((uint32_t)f2bf(b.w) << 16);
  *(uint4*)(d + i) = o;
}

// ---------------------------------------------------------------- QKV GEMM
// PROVEN 128x128/BK=64 2-barrier version (75.5us, 687 TF). Falsified
// alternatives on this workload: 8-phase 256^2 (92us), direct-A reg loads
// (237us), ring-3 BK=32 counted-vmcnt (85us), f32-staged-A (212us).
// Multi-block co-residency is the latency hider at these shapes.
#define BKG 64
__global__ __launch_bounds__(256) void gemm_qkv(
    const u16* __restrict__ Qb, const u16* __restrict__ Kb,
    const u16* __restrict__ Vb,
    const u16* __restrict__ Wq, const u16* __restrict__ Wk,
    const u16* __restrict__ Wv,
    const float* __restrict__ bq, const float* __restrict__ bk,
    const float* __restrict__ bv,
    u16* __restrict__ qo, u16* __restrict__ ko, u16* __restrict__ vo) {
  const u16* A; const u16* Bw; const float* bias; u16* Co;
  if (blockIdx.z == 0)      { A = Qb; Bw = Wq; bias = bq; Co = qo; }
  else if (blockIdx.z == 1) { A = Kb; Bw = Wk; bias = bk; Co = ko; }
  else                      { A = Vb; Bw = Wv; bias = bv; Co = vo; }

  __shared__ u16 As[128 * 64];
  __shared__ u16 Bs[128 * 64];

  const int tid  = threadIdx.x;
  const int wave = tid >> 6, lane = tid & 63;
  const int quad = lane >> 4, l16 = lane & 15;
  const int wm = wave >> 1, wn = wave & 1;
  const int m0 = blockIdx.x * 128, n0 = blockIdx.y * 128;

  const floatx4 FZ = {0.f, 0.f, 0.f, 0.f};
  floatx4 acc[4][4];
#pragma unroll
  for (int mt = 0; mt < 4; ++mt)
#pragma unroll
    for (int nt = 0; nt < 4; ++nt) acc[mt][nt] = FZ;

  for (int k0 = 0; k0 < DIM; k0 += BKG) {
    __syncthreads();
#pragma unroll
    for (int j = 0; j < 4; ++j) {
      int pc = j * 256 + tid;
      int r = pc >> 3, c = pc & 7;
      int sc = c ^ (r & 7);
      gl_lds16(A  + (size_t)(m0 + r) * DIM + k0 + sc * 8,
               &As[(j * 256 + wave * 64) * 8]);
      gl_lds16(Bw + (size_t)(n0 + r) * DIM + k0 + sc * 8,
               &Bs[(j * 256 + wave * 64) * 8]);
    }
    __syncthreads();

#pragma unroll
    for (int kk = 0; kk < 2; ++kk) {
      bf16x8 af[4], bfr[4];
#pragma unroll
      for (int mt = 0; mt < 4; ++mt) {
        int ra = wm * 64 + mt * 16 + l16;
        af[mt] = *(const bf16x8*)&As[ra * 64 + (((kk * 4 + quad) ^ (ra & 7)) * 8)];
      }
#pragma unroll
      for (int nt = 0; nt < 4; ++nt) {
        int rb = wn * 64 + nt * 16 + l16;
        bfr[nt] = *(const bf16x8*)&Bs[rb * 64 + (((kk * 4 + quad) ^ (rb & 7)) * 8)];
      }
#pragma unroll
      for (int mt = 0; mt < 4; ++mt)
#pragma unroll
        for (int nt = 0; nt < 4; ++nt)
          acc[mt][nt] = __builtin_amdgcn_mfma_f32_16x16x32_bf16(
              af[mt], bfr[nt], acc[mt][nt], 0, 0, 0);
    }
  }

  if (blockIdx.z == 2) {
    // V: transposed store to [B,H,HD,T], 8B packed (4 consecutive t)
#pragma unroll
    for (int nt = 0; nt < 4; ++nt) {
      int n = n0 + wn * 64 + nt * 16 + l16;
      float bb = bias[n];
      int h = n >> 6, hd = n & 63;
#pragma unroll
      for (int mt = 0; mt < 4; ++mt) {
        int mbase = m0 + wm * 64 + mt * 16 + quad * 4;
        int b = mbase >> 11, t = mbase & (T_SEQ - 1);
        u64 pk = 0;
#pragma unroll
        for (int r = 0; r < 4; ++r)
          pk |= (u64)f2bf(acc[mt][nt][r] + bb) << (16 * r);
        *(u64*)&Co[((size_t)((b * NH + h) * HD + hd)) * T_SEQ + t] = pk;
      }
    }
  } else {
    // Q/K: +bias (Q also * SCL_Q), bf16, scatter to [B,H,T,HD]
    const float sc = (blockIdx.z == 0) ? SCL_Q : 1.0f;
#pragma unroll
    for (int nt = 0; nt < 4; ++nt) {
      int n = n0 + wn * 64 + nt * 16 + l16;
      float bb = bias[n];
      int h = n >> 6, hd = n & 63;
#pragma unroll
      for (int mt = 0; mt < 4; ++mt) {
#pragma unroll
        for (int r = 0; r < 4; ++r) {
          int m = m0 + wm * 64 + mt * 16 + quad * 4 + r;
          int b = m >> 11, t = m & (T_SEQ - 1);
          Co[((size_t)(b * NH + h) * T_SEQ + t) * HD + hd] =
              f2bf((acc[mt][nt][r] + bb) * sc);
        }
      }
    }
  }
}

// ---------------------------------------------------------------- flash attn
// v4 (proven): 4 waves x 64 q-cols per wave (two 32-col q-sets per lane),
// 256 thr, 3-deep K/V pipeline, counted vmcnt(4), fixed-max softmax,
// permlane P-transpose. 512 blocks co-resident; heavy+light qt pairing.
__global__ __launch_bounds__(256, 2) void flash_attn(
    const u16* __restrict__ qp, const u16* __restrict__ kp,
    const u16* __restrict__ vp, u16* __restrict__ ao) {
  const int bh = blockIdx.x;                       // 0..63
  const int y = blockIdx.y;                        // 0..7
  const int qt = (y < 4) ? (7 - y) : (y - 4);      // heavy first + pairing
  const int b = bh >> 4, h = bh & 15;
  const u16* Qg = qp + (size_t)bh * T_SEQ * HD;
  const u16* Kg = kp + (size_t)bh * T_SEQ * HD;
  const u16* Vg = vp + (size_t)bh * HD * T_SEQ;    // [hd][t]

  __shared__ u16 lds[6][64 * 64];   // {K,V} x 3-deep, 48 KB

  const int tid = threadIdx.x, wave = tid >> 6, lane = tid & 63;
  const int hi = lane >> 5, c31 = lane & 31;
  const int lr8 = lane >> 3, lc8 = lane & 7;

  const int wbase = qt * 256 + wave * 64;   // wave's 64 q rows
  const int qrowA = wbase + c31;            // q-set A
  const int qrowB = qrowA + 32;             // q-set B

  bf16x8 bqA[4], bqB[4];
#pragma unroll
  for (int cth = 0; cth < 4; ++cth) {
    bqA[cth] = *(const bf16x8*)(Qg + (size_t)qrowA * HD + cth * 16 + hi * 8);
    bqB[cth] = *(const bf16x8*)(Qg + (size_t)qrowB * HD + cth * 16 + hi * 8);
  }

  const int nkb = 4 * qt + 4;   // kv tiles (>=4)

#define STAGE_KV(kbidx, bufpair)                                              \
  {                                                                           \
    const u16* Kgk = Kg + (size_t)(kbidx) * 64 * HD;                          \
    const u16* Vgk = Vg + (size_t)(kbidx) * 64;                               \
    _Pragma("unroll") for (int i_ = 0; i_ < 2; ++i_) {                        \
      int r_ = i_ * 32 + wave * 8 + lr8;                                      \
      int sc_ = lc8 ^ (r_ & 7);                                               \
      gl_lds16(Kgk + (size_t)r_ * HD + sc_ * 8,                               \
               &lds[(bufpair) * 2][(i_ * 32 + wave * 8) * 64]);               \
      gl_lds16(Vgk + (size_t)r_ * T_SEQ + sc_ * 8,                            \
               &lds[(bufpair) * 2 + 1][(i_ * 32 + wave * 8) * 64]);           \
    }                                                                         \
  }

  STAGE_KV(0, 0);
  STAGE_KV(1, 1);

  asm volatile("" :: "v"(bqA[0]), "v"(bqA[1]), "v"(bqA[2]), "v"(bqA[3]),
                     "v"(bqB[0]), "v"(bqB[1]), "v"(bqB[2]), "v"(bqB[3]));

  floatx16 oA0, oA1, oB0, oB1;   // O^T accum per set: hd 0..31 / 32..63
#pragma unroll
  for (int i = 0; i < 16; ++i) { oA0[i] = 0.f; oA1[i] = 0.f;
                                 oB0[i] = 0.f; oB1[i] = 0.f; }
  float l_pA = 0.f, l_pB = 0.f;  // lane-local softmax denominators

  int koff[4];
#pragma unroll
  for (int x = 0; x < 4; ++x)
    koff[x] = c31 * 64 + (((x * 2 + hi) ^ (c31 & 7)) * 8);

  int pcb = 0;   // compute buffer-pair
  int psb = 2;   // next stage buffer-pair
  for (int kb = 0; kb < nkb; ++kb) {
    if (kb + 1 < nkb) asm volatile("s_waitcnt vmcnt(4)" ::: "memory");
    else              asm volatile("s_waitcnt vmcnt(0)" ::: "memory");
    __builtin_amdgcn_s_barrier();
    __builtin_amdgcn_sched_barrier(0);

    if (kb + 2 < nkb) {   // stage tile kb+2 (lands ~2 compute phases later)
      STAGE_KV(kb + 2, psb);
      psb = (psb == 2) ? 0 : psb + 1;
    }

    if (kb * 64 <= wbase + 63) {
      const u16* Ks = &lds[pcb * 2][0];
      const u16* Vs = &lds[pcb * 2 + 1][0];

      floatx16 sA0, sA1, sB0, sB1;
#pragma unroll
      for (int i = 0; i < 16; ++i) { sA0[i] = 0.f; sA1[i] = 0.f;
                                     sB0[i] = 0.f; sB1[i] = 0.f; }
#pragma unroll
      for (int cth = 0; cth < 4; ++cth) {
        bf16x8 ka = *(const bf16x8*)&Ks[koff[cth]];
        bf16x8 kh = *(const bf16x8*)&Ks[koff[cth] + 32 * 64];
        sA0 = __builtin_amdgcn_mfma_f32_32x32x16_bf16(ka, bqA[cth], sA0, 0, 0, 0);
        sA1 = __builtin_amdgcn_mfma_f32_32x32x16_bf16(kh, bqA[cth], sA1, 0, 0, 0);
        sB0 = __builtin_amdgcn_mfma_f32_32x32x16_bf16(ka, bqB[cth], sB0, 0, 0, 0);
        sB1 = __builtin_amdgcn_mfma_f32_32x32x16_bf16(kh, bqB[cth], sB1, 0, 0, 0);
      }

      if (kb * 64 + 63 > wbase) {
        int kvb = kb * 64 + 4 * hi;
#pragma unroll
        for (int r = 0; r < 16; ++r) {
          int kvr = kvb + (r & 3) + 8 * (r >> 2);
          if (kvr > qrowA)      sA0[r] = -3e38f;
          if (kvr + 32 > qrowA) sA1[r] = -3e38f;
          if (kvr > qrowB)      sB0[r] = -3e38f;
          if (kvr + 32 > qrowB) sB1[r] = -3e38f;
        }
      }

      uint32_t pkA0[8], pkA1[8], pkB0[8], pkB1[8];
      float rsA = 0.f, rsB = 0.f;
#pragma unroll
      for (int rr = 0; rr < 8; ++rr) {
        union { float f; uint32_t u; } x0, x1, y0, y1;
        x0.f = __builtin_amdgcn_exp2f(sA0[2 * rr]);
        x1.f = __builtin_amdgcn_exp2f(sA0[2 * rr + 1]);
        y0.f = __builtin_amdgcn_exp2f(sA1[2 * rr]);
        y1.f = __builtin_amdgcn_exp2f(sA1[2 * rr + 1]);
        rsA += (x0.f + x1.f) + (y0.f + y1.f);
        pkA0[rr] = __builtin_amdgcn_perm(x1.u, x0.u, 0x07060302);
        pkA1[rr] = __builtin_amdgcn_perm(y1.u, y0.u, 0x07060302);
        x0.f = __builtin_amdgcn_exp2f(sB0[2 * rr]);
        x1.f = __builtin_amdgcn_exp2f(sB0[2 * rr + 1]);
        y0.f = __builtin_amdgcn_exp2f(sB1[2 * rr]);
        y1.f = __builtin_amdgcn_exp2f(sB1[2 * rr + 1]);
        rsB += (x0.f + x1.f) + (y0.f + y1.f);
        pkB0[rr] = __builtin_amdgcn_perm(x1.u, x0.u, 0x07060302);
        pkB1[rr] = __builtin_amdgcn_perm(y1.u, y0.u, 0x07060302);
      }
      l_pA += rsA;
      l_pB += rsB;

#pragma unroll
      for (int cc = 0; cc < 4; ++cc) {
        const uint32_t* pA = (cc & 2) ? pkA1 : pkA0;
        const uint32_t* pB = (cc & 2) ? pkB1 : pkB0;
        const int e4 = (cc & 1) * 4;
        auto a0 = __builtin_amdgcn_permlane32_swap(pA[e4 + 0], pA[e4 + 2],
                                                   false, false);
        auto a1 = __builtin_amdgcn_permlane32_swap(pA[e4 + 1], pA[e4 + 3],
                                                   false, false);
        auto b0 = __builtin_amdgcn_permlane32_swap(pB[e4 + 0], pB[e4 + 2],
                                                   false, false);
        auto b1 = __builtin_amdgcn_permlane32_swap(pB[e4 + 1], pB[e4 + 3],
                                                   false, false);
        union { uint32_t u[4]; bf16x8 v; } bpA, bpB;
        bpA.u[0] = a0[0]; bpA.u[1] = a1[0]; bpA.u[2] = a0[1]; bpA.u[3] = a1[1];
        bpB.u[0] = b0[0]; bpB.u[1] = b1[0]; bpB.u[2] = b0[1]; bpB.u[3] = b1[1];
        bf16x8 va = *(const bf16x8*)&Vs[koff[cc]];
        bf16x8 vb = *(const bf16x8*)&Vs[koff[cc] + 32 * 64];
        oA0 = __builtin_amdgcn_mfma_f32_32x32x16_bf16(va, bpA.v, oA0, 0, 0, 0);
        oA1 = __builtin_amdgcn_mfma_f32_32x32x16_bf16(vb, bpA.v, oA1, 0, 0, 0);
        oB0 = __builtin_amdgcn_mfma_f32_32x32x16_bf16(va, bpB.v, oB0, 0, 0, 0);
        oB1 = __builtin_amdgcn_mfma_f32_32x32x16_bf16(vb, bpB.v, oB1, 0, 0, 0);
      }
    }
    pcb = (pcb == 2) ? 0 : pcb + 1;
  }
#undef STAGE_KV

  {
    float lA = l_pA + __shfl_xor(l_pA, 32);
    float lB = l_pB + __shfl_xor(l_pB, 32);
    float invA = 1.0f / lA, invB = 1.0f / lB;
    const size_t obaseA = (size_t)(b * T_SEQ + qrowA) * DIM + h * HD;
    const size_t obaseB = obaseA + (size_t)32 * DIM;
#pragma unroll
    for (int u4 = 0; u4 < 4; ++u4) {
      u64 wA0 = 0, wA1 = 0, wB0 = 0, wB1 = 0;
#pragma unroll
      for (int r = 0; r < 4; ++r) {
        wA0 |= (u64)f2bf(oA0[4 * u4 + r] * invA) << (16 * r);
        wA1 |= (u64)f2bf(oA1[4 * u4 + r] * invA) << (16 * r);
        wB0 |= (u64)f2bf(oB0[4 * u4 + r] * invB) << (16 * r);
        wB1 |= (u64)f2bf(oB1[4 * u4 + r] * invB) << (16 * r);
      }
      *(u64*)&ao[obaseA + 8 * u4 + 4 * hi] = wA0;
      *(u64*)&ao[obaseA + 32 + 8 * u4 + 4 * hi] = wA1;
      *(u64*)&ao[obaseB + 8 * u4 + 4 * hi] = wB0;
      *(u64*)&ao[obaseB + 32 + 8 * u4 + 4 * hi] = wB1;
    }
  }
}

// ---------------------------------------------------------------- out GEMM
__global__ __launch_bounds__(256) void gemm_out(
    const u16* __restrict__ Ain, const u16* __restrict__ Wo,
    const float* __restrict__ bo, float* __restrict__ out) {
  __shared__ u16 As[128 * 64];
  __shared__ u16 Bs[128 * 64];

  const int tid  = threadIdx.x;
  const int wave = tid >> 6, lane = tid & 63;
  const int quad = lane >> 4, l16 = lane & 15;
  const int wm = wave >> 1, wn = wave & 1;
  const int m0 = blockIdx.x * 128, n0 = blockIdx.y * 128;

  const floatx4 FZ = {0.f, 0.f, 0.f, 0.f};
  floatx4 acc[4][4];
#pragma unroll
  for (int mt = 0; mt < 4; ++mt)
#pragma unroll
    for (int nt = 0; nt < 4; ++nt) acc[mt][nt] = FZ;

  for (int k0 = 0; k0 < DIM; k0 += BKG) {
    __syncthreads();
#pragma unroll
    for (int j = 0; j < 4; ++j) {
      int pc = j * 256 + tid;
      int r = pc >> 3, c = pc & 7;
      int sc = c ^ (r & 7);
      gl_lds16(Ain + (size_t)(m0 + r) * DIM + k0 + sc * 8,
               &As[(j * 256 + wave * 64) * 8]);
      gl_lds16(Wo  + (size_t)(n0 + r) * DIM + k0 + sc * 8,
               &Bs[(j * 256 + wave * 64) * 8]);
    }
    __syncthreads();

#pragma unroll
    for (int kk = 0; kk < 2; ++kk) {
      bf16x8 af[4], bfr[4];
#pragma unroll
      for (int mt = 0; mt < 4; ++mt) {
        int ra = wm * 64 + mt * 16 + l16;
        af[mt] = *(const bf16x8*)&As[ra * 64 + (((kk * 4 + quad) ^ (ra & 7)) * 8)];
      }
#pragma unroll
      for (int nt = 0; nt < 4; ++nt) {
        int rb = wn * 64 + nt * 16 + l16;
        bfr[nt] = *(const bf16x8*)&Bs[rb * 64 + (((kk * 4 + quad) ^ (rb & 7)) * 8)];
      }
#pragma unroll
      for (int mt = 0; mt < 4; ++mt)
#pragma unroll
        for (int nt = 0; nt < 4; ++nt)
          acc[mt][nt] = __builtin_amdgcn_mfma_f32_16x16x32_bf16(
              af[mt], bfr[nt], acc[mt][nt], 0, 0, 0);
    }
  }

#pragma unroll
  for (int nt = 0; nt < 4; ++nt) {
    int n = n0 + wn * 64 + nt * 16 + l16;
    float bb = bo[n];
#pragma unroll
    for (int mt = 0; mt < 4; ++mt)
#pragma unroll
      for (int r = 0; r < 4; ++r) {
        int m = m0 + wm * 64 + mt * 16 + quad * 4 + r;
        out[(size_t)m * DIM + n] = acc[mt][nt][r] + bb;
      }
  }
}

// ---------------------------------------------------------------- launch
extern "C" void kernel_launch(void* const* d_in, const int* in_sizes, int n_in,
                              void* d_out, int out_size, void* d_ws,
                              size_t ws_size, hipStream_t stream) {
  const float* Q  = (const float*)d_in[0];
  const float* K  = (const float*)d_in[1];
  const float* V  = (const float*)d_in[2];
  // d_in[3] = mask: tril causal, implemented analytically in flash_attn
  const float* Wq = (const float*)d_in[4];
  const float* bq = (const float*)d_in[5];
  const float* Wk = (const float*)d_in[6];
  const float* bk = (const float*)d_in[7];
  const float* Wv = (const float*)d_in[8];
  const float* bv = (const float*)d_in[9];
  const float* Wo = (const float*)d_in[10];
  const float* bo = (const float*)d_in[11];
  float* out = (float*)d_out;

  // workspace layout (u16 elements), total ~120 MiB
  u16* wqb = (u16*)d_ws;
  u16* wkb = wqb + 1048576;
  u16* wvb = wkb + 1048576;
  u16* wob = wvb + 1048576;
  u16* Qb  = wob + 1048576;             // activations bf16 [B,T,D]
  u16* Kb  = Qb + (size_t)M_TOT * DIM;
  u16* Vb  = Kb + (size_t)M_TOT * DIM;
  u16* qp  = Vb + (size_t)M_TOT * DIM;  // projected [B,H,T,HD] (q pre-scaled)
  u16* kp  = qp + (size_t)M_TOT * DIM;  // [B,H,T,HD]
  u16* vp  = kp + (size_t)M_TOT * DIM;  // [B,H,HD,T]  (pre-transposed)
  u16* aop = vp + (size_t)M_TOT * DIM;  // attn out [B,T,D] bf16

  cvt_all<<<dim3(M_TOT * DIM / 2048, 7), 256, 0, stream>>>(
      Wq, Wk, Wv, Wo, Q, K, V, wqb, wkb, wvb, wob, Qb, Kb, Vb);

  gemm_qkv<<<dim3(M_TOT / 128, DIM / 128, 3), 256, 0, stream>>>(
      Qb, Kb, Vb, wqb, wkb, wvb, bq, bk, bv, qp, kp, vp);

  flash_attn<<<dim3(B_SZ * NH, T_SEQ / 256), 256, 0, stream>>>(qp, kp, vp, aop);

  gemm_out<<<dim3(M_TOT / 128, DIM / 128), 256, 0, stream>>>(aop, wob, bo, out);
}